// Round 5
// baseline (147.476 us; speedup 1.0000x reference)
//
#include <hip/hip_runtime.h>

// ChoopyLoss: loss = -(1/B) * sum_{i,j} out[i,j] * r[i,j]
// where r[i,j] = 2*cum[i,j] / (j+1 + total_i)   (exact simplification of F1)
// B=2048, N=8192.
//
// R3 post-mortem: kernel was latency/VALU-bound (hot replays with data fully
// cache-resident still 42us; VALUBusy 27%). Culprits: 6-step ds_bpermute scan
// chains + exact f32 division (~10 ops/elem). This version uses ballot+mbcnt
// for the scan (no cross-lane latency chain) and v_rcp_f32 for the divide.

#define BLOCK 256
#define NROW 8192
#define PASSES 8   // NROW / (BLOCK*4)

__device__ __forceinline__ int mbcnt64(unsigned long long m) {
    // popcount(m & lanemask_lt)
    return __builtin_amdgcn_mbcnt_hi((unsigned)(m >> 32),
           __builtin_amdgcn_mbcnt_lo((unsigned)m, 0u));
}

__global__ __launch_bounds__(BLOCK) void f1_row_kernel(
    const float* __restrict__ outv,
    const int* __restrict__ labels,
    float* __restrict__ partials)
{
    const int row  = blockIdx.x;
    const int t    = threadIdx.x;
    const int lane = t & 63;
    const int wid  = t >> 6;

    const long long rowbase = (long long)row * NROW;
    const int*   lab = labels + rowbase;
    const float* op  = outv  + rowbase;

    __shared__ int wave_tot[PASSES][4];

    unsigned int mask = 0;   // 4 label bits per pass (this thread's 4 elements)
    int pre[PASSES];         // cross-lane count within wave before this lane's 4 elems

    // Phase 1: load labels (coalesced int4), ballot-scan per pass.
    #pragma unroll
    for (int p = 0; p < PASSES; ++p) {
        const int4 lv = *(const int4*)(lab + p * 1024 + t * 4);
        const int b0 = (lv.x != 0), b1 = (lv.y != 0), b2 = (lv.z != 0), b3 = (lv.w != 0);
        mask |= (unsigned)(b0 | (b1 << 1) | (b2 << 2) | (b3 << 3)) << (p * 4);
        const unsigned long long m0 = __ballot(b0);
        const unsigned long long m1 = __ballot(b1);
        const unsigned long long m2 = __ballot(b2);
        const unsigned long long m3 = __ballot(b3);
        pre[p] = mbcnt64(m0) + mbcnt64(m1) + mbcnt64(m2) + mbcnt64(m3);
        if (lane == 0) {
            // wave total: scalar popcounts of the (wave-uniform) ballot masks
            wave_tot[p][wid] = __popcll(m0) + __popcll(m1) + __popcll(m2) + __popcll(m3);
        }
    }
    __syncthreads();

    // Cross-wave / cross-pass bases and row total.
    int base[PASSES];
    int run = 0;
    #pragma unroll
    for (int p = 0; p < PASSES; ++p) {
        const int w0 = wave_tot[p][0], w1 = wave_tot[p][1],
                  w2 = wave_tot[p][2], w3 = wave_tot[p][3];
        const int wb = (wid > 0 ? w0 : 0) + (wid > 1 ? w1 : 0) + (wid > 2 ? w2 : 0);
        base[p] = run + wb + pre[p];     // exclusive count before this thread's 4 elems
        run += w0 + w1 + w2 + w3;
    }
    const float ftot = (float)run;       // row total (0 handled: cum==0 -> term 0)

    // Phase 2: load output (coalesced float4), accumulate out * 2*cum * rcp(k+total).
    float acc = 0.f;
    #pragma unroll
    for (int p = 0; p < PASSES; ++p) {
        const float4 ov = *(const float4*)(op + p * 1024 + t * 4);
        int c = base[p];
        const int kbase = p * 1024 + t * 4;       // element index; k = kbase + l + 1
        const unsigned nib = (mask >> (p * 4)) & 0xFu;
        c += (nib & 1u);
        acc = fmaf(ov.x, (float)(2 * c) * __builtin_amdgcn_rcpf((float)(kbase + 1) + ftot), acc);
        c += (nib >> 1) & 1u;
        acc = fmaf(ov.y, (float)(2 * c) * __builtin_amdgcn_rcpf((float)(kbase + 2) + ftot), acc);
        c += (nib >> 2) & 1u;
        acc = fmaf(ov.z, (float)(2 * c) * __builtin_amdgcn_rcpf((float)(kbase + 3) + ftot), acc);
        c += (nib >> 3) & 1u;
        acc = fmaf(ov.w, (float)(2 * c) * __builtin_amdgcn_rcpf((float)(kbase + 4) + ftot), acc);
    }

    // Block reduction of acc (wave shuffle + LDS across 4 waves).
    #pragma unroll
    for (int off = 32; off > 0; off >>= 1) acc += __shfl_down(acc, off, 64);
    __shared__ float wacc[4];
    if (lane == 0) wacc[wid] = acc;
    __syncthreads();
    if (t == 0) partials[row] = wacc[0] + wacc[1] + wacc[2] + wacc[3];
}

__global__ __launch_bounds__(256) void f1_finalize_kernel(
    const float* __restrict__ partials, float* __restrict__ out, int B)
{
    double s = 0.0;
    for (int i = threadIdx.x; i < B; i += 256) s += (double)partials[i];
    #pragma unroll
    for (int off = 32; off > 0; off >>= 1) s += __shfl_down(s, off, 64);
    __shared__ double ws[4];
    const int lane = threadIdx.x & 63, wid = threadIdx.x >> 6;
    if (lane == 0) ws[wid] = s;
    __syncthreads();
    if (threadIdx.x == 0) {
        out[0] = (float)(-(ws[0] + ws[1] + ws[2] + ws[3]) / (double)B);
    }
}

extern "C" void kernel_launch(void* const* d_in, const int* in_sizes, int n_in,
                              void* d_out, int out_size, void* d_ws, size_t ws_size,
                              hipStream_t stream) {
    const float* outv   = (const float*)d_in[0];   // [B, N, 1] f32
    const int*   labels = (const int*)d_in[1];     // [B, N] i32
    float* partials = (float*)d_ws;                // B floats of scratch
    float* result   = (float*)d_out;

    const int B = 2048;
    f1_row_kernel<<<B, BLOCK, 0, stream>>>(outv, labels, partials);
    f1_finalize_kernel<<<1, 256, 0, stream>>>(partials, result, B);
}

// Round 6
// 146.382 us; speedup vs baseline: 1.0075x; 1.0075x over previous
//
#include <hip/hip_runtime.h>

// ChoopyLoss: loss = -(1/B) * sum_{i,j} out[i,j] * r[i,j]
// where r[i,j] = 2*cum[i,j] / (j+1 + total_i)   (exact simplification of F1)
// B=2048, N=8192.
//
// R5 post-mortem: VGPR=28 => compiler serialized loads (MLP~1), kernel is
// memory-LATENCY bound (VALUBusy 15%, HBM 18%, both idle). This version
// issues all 16 loads per thread up front into register arrays (static
// indexing, unrolled) so ~16 loads stay in flight per wave.

#define BLOCK 256
#define NROW 8192
#define PASSES 8   // NROW / (BLOCK*4)

__device__ __forceinline__ int mbcnt64(unsigned long long m) {
    // popcount(m & lanemask_lt)
    return __builtin_amdgcn_mbcnt_hi((unsigned)(m >> 32),
           __builtin_amdgcn_mbcnt_lo((unsigned)m, 0u));
}

__global__ __launch_bounds__(BLOCK) void f1_row_kernel(
    const float* __restrict__ outv,
    const int* __restrict__ labels,
    float* __restrict__ partials)
{
    const int row  = blockIdx.x;
    const int t    = threadIdx.x;
    const int lane = t & 63;
    const int wid  = t >> 6;

    const long long rowbase = (long long)row * NROW;
    const int4*   lab4 = (const int4*)(labels + rowbase);
    const float4* op4  = (const float4*)(outv + rowbase);

    __shared__ int wave_tot[PASSES][4];

    // ---- Issue ALL loads up front (16 outstanding per thread) ----
    int4   lv[PASSES];
    float4 ov[PASSES];
    #pragma unroll
    for (int p = 0; p < PASSES; ++p) lv[p] = lab4[p * 256 + t];
    #pragma unroll
    for (int p = 0; p < PASSES; ++p) ov[p] = op4[p * 256 + t];

    // ---- Phase 1: ballot-scan per pass (uses lv; ov loads still in flight) ----
    unsigned int mask = 0;   // 4 label bits per pass (this thread's 4 elements)
    int pre[PASSES];         // cross-lane count within wave before this lane's 4 elems
    #pragma unroll
    for (int p = 0; p < PASSES; ++p) {
        const int b0 = (lv[p].x != 0), b1 = (lv[p].y != 0),
                  b2 = (lv[p].z != 0), b3 = (lv[p].w != 0);
        mask |= (unsigned)(b0 | (b1 << 1) | (b2 << 2) | (b3 << 3)) << (p * 4);
        const unsigned long long m0 = __ballot(b0);
        const unsigned long long m1 = __ballot(b1);
        const unsigned long long m2 = __ballot(b2);
        const unsigned long long m3 = __ballot(b3);
        pre[p] = mbcnt64(m0) + mbcnt64(m1) + mbcnt64(m2) + mbcnt64(m3);
        if (lane == 0) {
            wave_tot[p][wid] = __popcll(m0) + __popcll(m1) + __popcll(m2) + __popcll(m3);
        }
    }
    __syncthreads();

    // ---- Cross-wave / cross-pass bases and row total ----
    int base[PASSES];
    int run = 0;
    #pragma unroll
    for (int p = 0; p < PASSES; ++p) {
        const int w0 = wave_tot[p][0], w1 = wave_tot[p][1],
                  w2 = wave_tot[p][2], w3 = wave_tot[p][3];
        const int wb = (wid > 0 ? w0 : 0) + (wid > 1 ? w1 : 0) + (wid > 2 ? w2 : 0);
        base[p] = run + wb + pre[p];     // exclusive count before this thread's 4 elems
        run += w0 + w1 + w2 + w3;
    }
    const float ftot = (float)run;       // row total (0 handled: cum==0 -> term 0)

    // ---- Phase 2: accumulate out * 2*cum * rcp(k+total) ----
    float acc = 0.f;
    #pragma unroll
    for (int p = 0; p < PASSES; ++p) {
        int c = base[p];
        const int kbase = p * 1024 + t * 4;       // element index; k = kbase + l + 1
        const unsigned nib = (mask >> (p * 4)) & 0xFu;
        c += (nib & 1u);
        acc = fmaf(ov[p].x, (float)(2 * c) * __builtin_amdgcn_rcpf((float)(kbase + 1) + ftot), acc);
        c += (nib >> 1) & 1u;
        acc = fmaf(ov[p].y, (float)(2 * c) * __builtin_amdgcn_rcpf((float)(kbase + 2) + ftot), acc);
        c += (nib >> 2) & 1u;
        acc = fmaf(ov[p].z, (float)(2 * c) * __builtin_amdgcn_rcpf((float)(kbase + 3) + ftot), acc);
        c += (nib >> 3) & 1u;
        acc = fmaf(ov[p].w, (float)(2 * c) * __builtin_amdgcn_rcpf((float)(kbase + 4) + ftot), acc);
    }

    // ---- Block reduction ----
    #pragma unroll
    for (int off = 32; off > 0; off >>= 1) acc += __shfl_down(acc, off, 64);
    __shared__ float wacc[4];
    if (lane == 0) wacc[wid] = acc;
    __syncthreads();
    if (t == 0) partials[row] = wacc[0] + wacc[1] + wacc[2] + wacc[3];
}

__global__ __launch_bounds__(256) void f1_finalize_kernel(
    const float* __restrict__ partials, float* __restrict__ out, int B)
{
    double s = 0.0;
    for (int i = threadIdx.x; i < B; i += 256) s += (double)partials[i];
    #pragma unroll
    for (int off = 32; off > 0; off >>= 1) s += __shfl_down(s, off, 64);
    __shared__ double ws[4];
    const int lane = threadIdx.x & 63, wid = threadIdx.x >> 6;
    if (lane == 0) ws[wid] = s;
    __syncthreads();
    if (threadIdx.x == 0) {
        out[0] = (float)(-(ws[0] + ws[1] + ws[2] + ws[3]) / (double)B);
    }
}

extern "C" void kernel_launch(void* const* d_in, const int* in_sizes, int n_in,
                              void* d_out, int out_size, void* d_ws, size_t ws_size,
                              hipStream_t stream) {
    const float* outv   = (const float*)d_in[0];   // [B, N, 1] f32
    const int*   labels = (const int*)d_in[1];     // [B, N] i32
    float* partials = (float*)d_ws;                // B floats of scratch
    float* result   = (float*)d_out;

    const int B = 2048;
    f1_row_kernel<<<B, BLOCK, 0, stream>>>(outv, labels, partials);
    f1_finalize_kernel<<<1, 256, 0, stream>>>(partials, result, B);
}

// Round 10
// 144.648 us; speedup vs baseline: 1.0196x; 1.0120x over previous
//
#include <hip/hip_runtime.h>

// ChoopyLoss: loss = -(1/B) * sum_{i,j} out[i,j] * r[i,j]
// where r[i,j] = 2*cum[i,j] / (j+1 + total_i)   (exact simplification of F1)
// B=2048, N=8192.
//
// R6 post-mortem: block-per-row with __syncthreads forces vmcnt(0) drains ->
// lockstep phases, ~2 wave-loads in flight per CU, 1.6 TB/s. This version:
// ONE WAVE PER ROW. No LDS, no barriers, no vmcnt(0) drains. Two streamed
// passes (labels then out), software-pipelined in groups of 8 chunks so ~8
// loads stay in flight per wave. Label bits stashed in 2 x u64 per lane so
// pass 2 never reloads labels.

#define NROW 8192
#define WAVES_PER_BLOCK 4
#define BLOCK (64 * WAVES_PER_BLOCK)
#define NCHUNK 32          // 8192 / (64 lanes * 4 elems per lane)
#define GRP 8              // chunks per pipeline group
#define NGRP (NCHUNK / GRP)

__device__ __forceinline__ int mbcnt64(unsigned long long m) {
    // popcount(m & lanemask_lt)
    return __builtin_amdgcn_mbcnt_hi((unsigned)(m >> 32),
           __builtin_amdgcn_mbcnt_lo((unsigned)m, 0u));
}

__global__ __launch_bounds__(BLOCK) void f1_row_kernel(
    const float* __restrict__ outv,
    const int* __restrict__ labels,
    float* __restrict__ partials)
{
    const int t    = threadIdx.x;
    const int lane = t & 63;
    const int wid  = t >> 6;
    const int row  = blockIdx.x * WAVES_PER_BLOCK + wid;

    const long long rowbase = (long long)row * NROW;
    const int4*   lab4 = (const int4*)(labels + rowbase);
    const float4* op4  = (const float4*)(outv + rowbase);

    // ---------------- PASS 1: stream labels, stash bits, row total ----------
    unsigned long long mlo = 0ull, mhi = 0ull;   // 4 bits/chunk; chunks 0..15 -> mlo
    int run = 0;                                  // row total (wave-uniform)

    int4 bufA[GRP], bufB[GRP];
    #pragma unroll
    for (int i = 0; i < GRP; ++i) bufA[i] = lab4[i * 64 + lane];

    // groups 0..NGRP-2: load next group, process current
    #pragma unroll
    for (int g = 0; g < NGRP - 1; ++g) {
        #pragma unroll
        for (int i = 0; i < GRP; ++i) {
            const int4 v = lab4[(g + 1) * GRP * 64 + i * 64 + lane];
            if (g & 1) bufA[i] = v; else bufB[i] = v;
        }
        #pragma unroll
        for (int i = 0; i < GRP; ++i) {
            const int4 lv = (g & 1) ? bufB[i] : bufA[i];
            const int c = g * GRP + i;
            const int b0 = (lv.x != 0), b1 = (lv.y != 0), b2 = (lv.z != 0), b3 = (lv.w != 0);
            const unsigned long long m0 = __ballot(b0), m1 = __ballot(b1),
                                     m2 = __ballot(b2), m3 = __ballot(b3);
            run += __popcll(m0) + __popcll(m1) + __popcll(m2) + __popcll(m3);
            const unsigned long long nib =
                (unsigned long long)(b0 | (b1 << 1) | (b2 << 2) | (b3 << 3));
            if (c < 16) mlo |= nib << (c * 4); else mhi |= nib << ((c - 16) * 4);
        }
    }

    // issue pass-2 prologue loads BEFORE processing the last label group,
    // so the memory pipe stays busy across the pass boundary
    float4 fA[GRP], fB[GRP];
    #pragma unroll
    for (int i = 0; i < GRP; ++i) fA[i] = op4[i * 64 + lane];

    // process last label group
    {
        const int g = NGRP - 1;
        #pragma unroll
        for (int i = 0; i < GRP; ++i) {
            const int4 lv = (g & 1) ? bufB[i] : bufA[i];
            const int c = g * GRP + i;
            const int b0 = (lv.x != 0), b1 = (lv.y != 0), b2 = (lv.z != 0), b3 = (lv.w != 0);
            const unsigned long long m0 = __ballot(b0), m1 = __ballot(b1),
                                     m2 = __ballot(b2), m3 = __ballot(b3);
            run += __popcll(m0) + __popcll(m1) + __popcll(m2) + __popcll(m3);
            const unsigned long long nib =
                (unsigned long long)(b0 | (b1 << 1) | (b2 << 2) | (b3 << 3));
            if (c < 16) mlo |= nib << (c * 4); else mhi |= nib << ((c - 16) * 4);
        }
    }

    const float ftot = (float)run;   // total==0 is fine: cum==0 -> every term 0

    // ---------------- PASS 2: stream out, weighted accumulate ---------------
    float acc = 0.f;
    int runbase = 0;
    #pragma unroll
    for (int g = 0; g < NGRP; ++g) {
        if (g + 1 < NGRP) {
            #pragma unroll
            for (int i = 0; i < GRP; ++i) {
                const float4 v = op4[(g + 1) * GRP * 64 + i * 64 + lane];
                if (g & 1) fA[i] = v; else fB[i] = v;
            }
        }
        #pragma unroll
        for (int i = 0; i < GRP; ++i) {
            const float4 ov = (g & 1) ? fB[i] : fA[i];
            const int c = g * GRP + i;
            const unsigned nib = (unsigned)(((c < 16) ? (mlo >> (c * 4))
                                                      : (mhi >> ((c - 16) * 4))) & 0xFull);
            const int b0 = nib & 1, b1 = (nib >> 1) & 1, b2 = (nib >> 2) & 1, b3 = (nib >> 3) & 1;
            const unsigned long long m0 = __ballot(b0), m1 = __ballot(b1),
                                     m2 = __ballot(b2), m3 = __ballot(b3);
            int cum = runbase + mbcnt64(m0) + mbcnt64(m1) + mbcnt64(m2) + mbcnt64(m3);
            const int kbase = c * 256 + lane * 4;   // 0-based elem index; k = kbase+i+1
            cum += b0;
            acc = fmaf(ov.x, (float)(2 * cum) * __builtin_amdgcn_rcpf((float)(kbase + 1) + ftot), acc);
            cum += b1;
            acc = fmaf(ov.y, (float)(2 * cum) * __builtin_amdgcn_rcpf((float)(kbase + 2) + ftot), acc);
            cum += b2;
            acc = fmaf(ov.z, (float)(2 * cum) * __builtin_amdgcn_rcpf((float)(kbase + 3) + ftot), acc);
            cum += b3;
            acc = fmaf(ov.w, (float)(2 * cum) * __builtin_amdgcn_rcpf((float)(kbase + 4) + ftot), acc);
            runbase += __popcll(m0) + __popcll(m1) + __popcll(m2) + __popcll(m3);
        }
    }

    // ---------------- wave-internal reduction, one write per row ------------
    #pragma unroll
    for (int off = 32; off > 0; off >>= 1) acc += __shfl_down(acc, off, 64);
    if (lane == 0) partials[row] = acc;
}

__global__ __launch_bounds__(256) void f1_finalize_kernel(
    const float* __restrict__ partials, float* __restrict__ out, int B)
{
    double s = 0.0;
    for (int i = threadIdx.x; i < B; i += 256) s += (double)partials[i];
    #pragma unroll
    for (int off = 32; off > 0; off >>= 1) s += __shfl_down(s, off, 64);
    __shared__ double ws[4];
    const int lane = threadIdx.x & 63, wid = threadIdx.x >> 6;
    if (lane == 0) ws[wid] = s;
    __syncthreads();
    if (threadIdx.x == 0) {
        out[0] = (float)(-(ws[0] + ws[1] + ws[2] + ws[3]) / (double)B);
    }
}

extern "C" void kernel_launch(void* const* d_in, const int* in_sizes, int n_in,
                              void* d_out, int out_size, void* d_ws, size_t ws_size,
                              hipStream_t stream) {
    const float* outv   = (const float*)d_in[0];   // [B, N, 1] f32
    const int*   labels = (const int*)d_in[1];     // [B, N] i32
    float* partials = (float*)d_ws;                // B floats of scratch
    float* result   = (float*)d_out;

    const int B = 2048;
    f1_row_kernel<<<B / WAVES_PER_BLOCK, BLOCK, 0, stream>>>(outv, labels, partials);
    f1_finalize_kernel<<<1, 256, 0, stream>>>(partials, result, B);
}